// Round 10
// baseline (344.888 us; speedup 1.0000x reference)
//
#include <hip/hip_runtime.h>
#include <hip/hip_bf16.h>

// Problem constants (CausalMultiHeadSelfAttention): B=4, S=2048, E=1024, H=16, D=64
#define E_DIM 1024
#define N_HEADS 16
#define HEAD_D 64
#define BATCH 4
#define SEQ 2048
#define M_ROWS (BATCH * SEQ)  // 8192
#define SCALE2 0.1803368801111244f  // 0.125 * log2(e): folded into Q at projection

typedef __attribute__((ext_vector_type(4))) float f32x4;
typedef __attribute__((ext_vector_type(8))) short s16x8;  // 8 bf16 in 4 VGPRs
typedef unsigned uint2v __attribute__((ext_vector_type(2)));

__device__ __forceinline__ unsigned short f2b(float f) {
  union { float f; unsigned u; } v; v.f = f;
  unsigned r = v.u + 0x7fffu + ((v.u >> 16) & 1u);  // RNE
  return (unsigned short)(r >> 16);
}

__device__ __forceinline__ unsigned packbf2(float lo, float hi) {
  union { __hip_bfloat162 h; unsigned u; } p;
  p.h = __float22bfloat162_rn(float2{lo, hi});  // v_cvt_pk_bf16_f32
  return p.u;
}

__device__ __forceinline__ void gld16(const void* g, void* l) {
  __builtin_amdgcn_global_load_lds(
      (__attribute__((address_space(1))) void*)(g),
      (__attribute__((address_space(3))) void*)(l), 16, 0, 0);
}

// lane-bit5 <-> reg swap (T12)
__device__ __forceinline__ void swap32(unsigned& a, unsigned& b, bool hi5) {
#if __has_builtin(__builtin_amdgcn_permlane32_swap)
  uint2v r = __builtin_amdgcn_permlane32_swap(a, b, false, false);
  a = r[0]; b = r[1];
#else
  unsigned x = hi5 ? a : b;
  x = __shfl_xor(x, 32, 64);
  unsigned na = hi5 ? x : a;
  b = hi5 ? b : x;
  a = na;
#endif
}
// lane-bit4 <-> reg swap
__device__ __forceinline__ void swap16(unsigned& a, unsigned& b, bool hi4) {
#if __has_builtin(__builtin_amdgcn_permlane16_swap)
  uint2v r = __builtin_amdgcn_permlane16_swap(a, b, false, false);
  a = r[0]; b = r[1];
#else
  unsigned x = hi4 ? a : b;
  x = __shfl_xor(x, 16, 64);
  unsigned na = hi4 ? x : a;
  b = hi4 ? b : x;
  a = na;
#endif
}

// ---------------- cast x (fp32 -> bf16), vectorized ----------------
__global__ __launch_bounds__(256) void cast_x_kernel(const float* __restrict__ in,
                                                     unsigned short* __restrict__ out,
                                                     int n4) {
  int i = blockIdx.x * 256 + threadIdx.x;
  const int stride = gridDim.x * 256;
  for (; i < n4; i += stride) {
    float4 v = ((const float4*)in)[i];
    ushort4 o;
    o.x = f2b(v.x); o.y = f2b(v.y); o.z = f2b(v.z); o.w = f2b(v.w);
    ((ushort4*)out)[i] = o;
  }
}

// ------- fused weight transpose+cast: 4 weights in one launch (grid.z) -------
__global__ __launch_bounds__(256) void wtrans4_kernel(const float* __restrict__ W0,
                                                      const float* __restrict__ W1,
                                                      const float* __restrict__ W2,
                                                      const float* __restrict__ W3,
                                                      unsigned short* __restrict__ D0,
                                                      unsigned short* __restrict__ D1,
                                                      unsigned short* __restrict__ D2,
                                                      unsigned short* __restrict__ D3) {
  const int z = blockIdx.z;
  const float* W = (z == 0) ? W0 : (z == 1) ? W1 : (z == 2) ? W2 : W3;
  unsigned short* WT = (z == 0) ? D0 : (z == 1) ? D1 : (z == 2) ? D2 : D3;
  __shared__ float t[64][65];
  const int k0 = blockIdx.x * 64, n0 = blockIdx.y * 64;
  const int tid = threadIdx.x;
  const int rr = tid >> 4, cc = (tid & 15) * 4;
  for (int p = 0; p < 4; ++p) {
    int row = p * 16 + rr;
    float4 v = *(const float4*)&W[(size_t)(k0 + row) * E_DIM + n0 + cc];
    t[row][cc] = v.x; t[row][cc + 1] = v.y; t[row][cc + 2] = v.z; t[row][cc + 3] = v.w;
  }
  __syncthreads();
  for (int p = 0; p < 4; ++p) {
    int nrow = p * 16 + rr;
    ushort4 o;
    o.x = f2b(t[cc][nrow]); o.y = f2b(t[cc + 1][nrow]);
    o.z = f2b(t[cc + 2][nrow]); o.w = f2b(t[cc + 3][nrow]);
    *(ushort4*)&WT[(size_t)(n0 + nrow) * E_DIM + k0 + cc] = o;
  }
}

// ---------------- fused QKV GEMM: 128x128 tile (round-8 config, 2 blocks/CU) ----------------
// Double-buffered LDS, issue-early staging, T2 XOR swizzle. 2 blocks/CU give
// cross-block overlap that hides the 2-phase barrier drain (round-9 lesson:
// 256x128 @ 1 block/CU regressed 91->103us). Q pre-scaled by SCALE2.
__global__ __launch_bounds__(256) void gemm_qkv(const unsigned short* __restrict__ A,
                                                const unsigned short* __restrict__ BT,
                                                const float* __restrict__ bq,
                                                const float* __restrict__ bk,
                                                const float* __restrict__ bv,
                                                unsigned short* __restrict__ Qb,
                                                unsigned short* __restrict__ Kb,
                                                unsigned short* __restrict__ Vt) {
  __shared__ unsigned short Al[2][8192];
  __shared__ unsigned short Bl[2][8192];
  const int K = E_DIM;
  const int tid = threadIdx.x;
  const int lane = tid & 63;
  const int wave = tid >> 6;
  const int wr = wave >> 1, wc = wave & 1;
  const int m0 = blockIdx.x * 128, n0 = blockIdx.y * 128;
  const int lrow = lane & 15, lg = lane >> 4;

  f32x4 acc[4][4] = {};

  const int ob = tid << 4;
  const int dstb = (wave << 10);
  int srow[4], scol[4];
#pragma unroll
  for (int p = 0; p < 4; ++p) {
    int o = p * 4096 + ob;
    srow[p] = o >> 7;
    scol[p] = ((o ^ ((srow[p] & 7) << 4)) & 127) >> 1;
  }

  auto stage = [&](int buf, int k0) {
#pragma unroll
    for (int p = 0; p < 4; ++p) {
      gld16((const void*)(A + (size_t)(m0 + srow[p]) * K + k0 + scol[p]),
            (void*)((char*)&Al[buf][0] + p * 4096 + dstb));
      gld16((const void*)(BT + (size_t)(n0 + srow[p]) * K + k0 + scol[p]),
            (void*)((char*)&Bl[buf][0] + p * 4096 + dstb));
    }
  };

  const int swz = (lrow & 7) << 4;

  stage(0, 0);
  __syncthreads();
  int cur = 0;
  const int nt = K / 64;

  for (int t = 0; t < nt; ++t) {
    if (t + 1 < nt) stage(cur ^ 1, (t + 1) * 64);
    const char* Ac = (const char*)&Al[cur][0];
    const char* Bc = (const char*)&Bl[cur][0];
#pragma unroll
    for (int ks = 0; ks < 2; ++ks) {
      const int cb = ks * 64 + lg * 16;
      s16x8 af[4], bf_[4];
#pragma unroll
      for (int i = 0; i < 4; ++i)
        af[i] = *(const s16x8*)(Ac + (((wr * 64 + i * 16 + lrow) * 128 + cb) ^ swz));
#pragma unroll
      for (int j = 0; j < 4; ++j)
        bf_[j] = *(const s16x8*)(Bc + (((wc * 64 + j * 16 + lrow) * 128 + cb) ^ swz));
#pragma unroll
      for (int i = 0; i < 4; ++i)
#pragma unroll
        for (int j = 0; j < 4; ++j)
          acc[i][j] = __builtin_amdgcn_mfma_f32_16x16x32_bf16(af[i], bf_[j], acc[i][j], 0, 0, 0);
    }
    __syncthreads();
    cur ^= 1;
  }

  for (int j = 0; j < 4; ++j) {
    int c = n0 + wc * 64 + j * 16 + lrow;   // global col in [0,3072)
    int proj = c >> 10, cc = c & 1023;
    float bvl = (proj == 0) ? bq[cc] : (proj == 1) ? bk[cc] : bv[cc];
    for (int i = 0; i < 4; ++i) {
      int r0 = m0 + wr * 64 + i * 16 + (lg << 2);
      for (int r = 0; r < 4; ++r) {
        float val = acc[i][j][r] + bvl;
        int m = r0 + r;
        if (proj == 0) {
          Qb[(size_t)m * E_DIM + cc] = f2b(val * SCALE2);  // pre-scaled Q
        } else if (proj == 1) {
          Kb[(size_t)m * E_DIM + cc] = f2b(val);
        } else {
          int b = m >> 11, s = m & 2047;
          int h = cc >> 6, d = cc & 63;
          Vt[((size_t)((b * 16 + h) * 64 + d)) * SEQ + s] = f2b(val);
        }
      }
    }
  }
}

// ---------------- output projection GEMM (f32 out), round-8 config ----------------
__global__ __launch_bounds__(256) void gemm_out(const unsigned short* __restrict__ A,
                                                const unsigned short* __restrict__ BT,
                                                const float* __restrict__ bias,
                                                float* __restrict__ C) {
  __shared__ unsigned short Al[2][8192];
  __shared__ unsigned short Bl[2][8192];
  const int K = E_DIM, N = E_DIM;
  const int tid = threadIdx.x;
  const int lane = tid & 63;
  const int wave = tid >> 6;
  const int wr = wave >> 1, wc = wave & 1;
  const int m0 = blockIdx.x * 128, n0 = blockIdx.y * 128;
  const int lrow = lane & 15, lg = lane >> 4;

  f32x4 acc[4][4] = {};

  const int ob = tid << 4;
  const int dstb = (wave << 10);
  int srow[4], scol[4];
#pragma unroll
  for (int p = 0; p < 4; ++p) {
    int o = p * 4096 + ob;
    srow[p] = o >> 7;
    scol[p] = ((o ^ ((srow[p] & 7) << 4)) & 127) >> 1;
  }

  auto stage = [&](int buf, int k0) {
#pragma unroll
    for (int p = 0; p < 4; ++p) {
      gld16((const void*)(A + (size_t)(m0 + srow[p]) * K + k0 + scol[p]),
            (void*)((char*)&Al[buf][0] + p * 4096 + dstb));
      gld16((const void*)(BT + (size_t)(n0 + srow[p]) * K + k0 + scol[p]),
            (void*)((char*)&Bl[buf][0] + p * 4096 + dstb));
    }
  };

  const int swz = (lrow & 7) << 4;

  stage(0, 0);
  __syncthreads();
  int cur = 0;
  const int nt = K / 64;

  for (int t = 0; t < nt; ++t) {
    if (t + 1 < nt) stage(cur ^ 1, (t + 1) * 64);
    const char* Ac = (const char*)&Al[cur][0];
    const char* Bc = (const char*)&Bl[cur][0];
#pragma unroll
    for (int ks = 0; ks < 2; ++ks) {
      const int cb = ks * 64 + lg * 16;
      s16x8 af[4], bf_[4];
#pragma unroll
      for (int i = 0; i < 4; ++i)
        af[i] = *(const s16x8*)(Ac + (((wr * 64 + i * 16 + lrow) * 128 + cb) ^ swz));
#pragma unroll
      for (int j = 0; j < 4; ++j)
        bf_[j] = *(const s16x8*)(Bc + (((wc * 64 + j * 16 + lrow) * 128 + cb) ^ swz));
#pragma unroll
      for (int i = 0; i < 4; ++i)
#pragma unroll
        for (int j = 0; j < 4; ++j)
          acc[i][j] = __builtin_amdgcn_mfma_f32_16x16x32_bf16(af[i], bf_[j], acc[i][j], 0, 0, 0);
    }
    __syncthreads();
    cur ^= 1;
  }

  for (int j = 0; j < 4; ++j) {
    int col = n0 + wc * 64 + j * 16 + lrow;
    float bvl = bias[col];
    for (int i = 0; i < 4; ++i) {
      int r0 = m0 + wr * 64 + i * 16 + (lg << 2);
      for (int r = 0; r < 4; ++r)
        C[(size_t)(r0 + r) * N + col] = acc[i][j][r] + bvl;
    }
  }
}

// ---------------- causal flash attention v8 (= v7 + 4 blocks/CU) ----------------
// v7 measured VGPR=84 at (256,2) with Occupancy only 22% -> the 2-block hint
// was the limiter, not registers. (256,4) caps VGPR at 128 (84 used, no spill
// risk) and doubles resident blocks -> more cross-block latency hiding.
__global__ __launch_bounds__(256, 4) void attn8_kernel(const unsigned short* __restrict__ Qb,
                                                       const unsigned short* __restrict__ Kb,
                                                       const unsigned short* __restrict__ Vt,
                                                       unsigned short* __restrict__ Ob) {
  __shared__ unsigned short Kl[2][4096];
  __shared__ unsigned short Vl[2][4096];

  const int tid = threadIdx.x, lane = tid & 63, wave = tid >> 6;
  const int id = blockIdx.x;
  const int xcd = id & 7;
  const int slot = id >> 3;
  const int bh = (xcd << 3) | (slot >> 4);
  const int ip = slot & 15;
  const size_t base = (size_t)(bh >> 4) * SEQ * E_DIM + (size_t)(bh & 15) * HEAD_D;
  const size_t baset = (size_t)bh * HEAD_D * SEQ;
  const int lq = lane & 15, lg = lane >> 4;

  const int row_lo = ip * 64 + wave * 16 + lq;
  const int row_hi = (31 - ip) * 64 + wave * 16 + lq;

  s16x8 qf0[2], qf1[2];
  {
    const unsigned short* p0 = Qb + base + (size_t)row_lo * E_DIM + lg * 8;
    qf0[0] = *(const s16x8*)p0; qf0[1] = *(const s16x8*)(p0 + 32);
    const unsigned short* p1 = Qb + base + (size_t)row_hi * E_DIM + lg * 8;
    qf1[0] = *(const s16x8*)p1; qf1[1] = *(const s16x8*)(p1 + 32);
  }

  const short onebf = (short)0x3F80;
  const s16x8 ones = {onebf, onebf, onebf, onebf, onebf, onebf, onebf, onebf};

  float m0r = -1e30f, m1r = -1e30f;
  f32x4 o0[4] = {}, o1[4] = {};
  f32x4 l0 = {}, l1 = {};
  const int ntm1 = 31 - ip;
  const bool hi5 = (lane & 32) != 0, hi4 = (lane & 16) != 0;

  const int o0b = tid << 4;
  const int o1b = 4096 + (tid << 4);
  const int r0s = o0b >> 7, r1s = o1b >> 7;
  const int c0s = ((o0b ^ ((r0s & 7) << 4)) & 127) >> 1;
  const int c1s = ((o1b ^ ((r1s & 7) << 4)) & 127) >> 1;
  const int dst0 = wave << 10;
  const int dst1 = 4096 + (wave << 10);

  auto stage = [&](int buf, int k0) {
    gld16((const void*)(Kb + base + (size_t)(k0 + r0s) * E_DIM + c0s),
          (void*)((char*)&Kl[buf][0] + dst0));
    gld16((const void*)(Kb + base + (size_t)(k0 + r1s) * E_DIM + c1s),
          (void*)((char*)&Kl[buf][0] + dst1));
    gld16((const void*)(Vt + baset + (size_t)r0s * SEQ + k0 + c0s),
          (void*)((char*)&Vl[buf][0] + dst0));
    gld16((const void*)(Vt + baset + (size_t)r1s * SEQ + k0 + c1s),
          (void*)((char*)&Vl[buf][0] + dst1));
  };

  const int swz = (lq & 7) << 4;

  auto process = [&](f32x4 (&sv)[4], int qrow, bool diag, float& mreg,
                     f32x4 (&oacc)[4], f32x4& lacc, int kk0, s16x8 (&vf)[4][2]) {
    if (diag) {
#pragma unroll
      for (int kb = 0; kb < 4; ++kb)
#pragma unroll
        for (int r = 0; r < 4; ++r) {
          int kk = kk0 + kb * 16 + lg * 4 + r;
          if (kk > qrow) sv[kb][r] = -1e30f;
        }
    }
    float t0, t1, mk[4];
#pragma unroll
    for (int kb = 0; kb < 4; ++kb) {
      t0 = fmaxf(sv[kb][0], sv[kb][1]);
      t1 = fmaxf(sv[kb][2], sv[kb][3]);
      mk[kb] = fmaxf(t0, t1);
    }
    float mx = fmaxf(fmaxf(mk[0], mk[1]), fmaxf(mk[2], mk[3]));
    mx = fmaxf(mx, __shfl_xor(mx, 16, 64));
    mx = fmaxf(mx, __shfl_xor(mx, 32, 64));
    if (!__all(mx - mreg <= 8.0f)) {
      float mn = fmaxf(mreg, mx);
      float corr = __builtin_amdgcn_exp2f(mreg - mn);
#pragma unroll
      for (int db = 0; db < 4; ++db) oacc[db] = oacc[db] * corr;
      lacc = lacc * corr;
      mreg = mn;
    }
    const float mn = mreg;
    unsigned c[4][2];
#pragma unroll
    for (int kb = 0; kb < 4; ++kb)
#pragma unroll
      for (int rp = 0; rp < 2; ++rp) {
        float plo = __builtin_amdgcn_exp2f(sv[kb][2 * rp] - mn);
        float phi = __builtin_amdgcn_exp2f(sv[kb][2 * rp + 1] - mn);
        c[kb][rp] = packbf2(plo, phi);
      }
#pragma unroll
    for (int k1 = 0; k1 < 2; ++k1)
#pragma unroll
      for (int rp = 0; rp < 2; ++rp)
        swap32(c[2 * k1][rp], c[2 * k1 + 1][rp], hi5);
#pragma unroll
    for (int k1 = 0; k1 < 2; ++k1)
#pragma unroll
      for (int rp = 0; rp < 2; ++rp)
        swap16(c[2 * k1][rp], c[2 * k1 + 1][rp], hi4);
#pragma unroll
    for (int ks = 0; ks < 2; ++ks) {
      union { unsigned w[4]; s16x8 v; } pu;
      pu.w[0] = c[2 * ks][0]; pu.w[1] = c[2 * ks][1];
      pu.w[2] = c[2 * ks + 1][0]; pu.w[3] = c[2 * ks + 1][1];
      lacc = __builtin_amdgcn_mfma_f32_16x16x32_bf16(ones, pu.v, lacc, 0, 0, 0);
#pragma unroll
      for (int db = 0; db < 4; ++db)
        oacc[db] = __builtin_amdgcn_mfma_f32_16x16x32_bf16(vf[db][ks], pu.v, oacc[db], 0, 0, 0);
    }
  };

  stage(0, 0);
  __syncthreads();
  int cur = 0;

  for (int t = 0; t <= ntm1; ++t) {
    if (t < ntm1) stage(cur ^ 1, (t + 1) * 64);

    const char* Kc = (const char*)&Kl[cur][0];
    const char* Vc = (const char*)&Vl[cur][0];
    s16x8 kf[4][2];
#pragma unroll
    for (int kb = 0; kb < 4; ++kb)
#pragma unroll
      for (int j = 0; j < 2; ++j)
        kf[kb][j] = *(const s16x8*)(Kc + (((kb * 16 + lq) * 128 + j * 64 + lg * 16) ^ swz));
    s16x8 vf[4][2];
#pragma unroll
    for (int db = 0; db < 4; ++db)
#pragma unroll
      for (int ks = 0; ks < 2; ++ks)
        vf[db][ks] = *(const s16x8*)(Vc + (((db * 16 + lq) * 128 + ks * 64 + lg * 16) ^ swz));

    const int kk0 = t * 64;
    {
      f32x4 s1v[4] = {};
#pragma unroll
      for (int kb = 0; kb < 4; ++kb) {
        s1v[kb] = __builtin_amdgcn_mfma_f32_16x16x32_bf16(kf[kb][0], qf1[0], s1v[kb], 0, 0, 0);
        s1v[kb] = __builtin_amdgcn_mfma_f32_16x16x32_bf16(kf[kb][1], qf1[1], s1v[kb], 0, 0, 0);
      }
      process(s1v, row_hi, t == ntm1, m1r, o1, l1, kk0, vf);
    }
    if (t <= ip) {
      f32x4 s0v[4] = {};
#pragma unroll
      for (int kb = 0; kb < 4; ++kb) {
        s0v[kb] = __builtin_amdgcn_mfma_f32_16x16x32_bf16(kf[kb][0], qf0[0], s0v[kb], 0, 0, 0);
        s0v[kb] = __builtin_amdgcn_mfma_f32_16x16x32_bf16(kf[kb][1], qf0[1], s0v[kb], 0, 0, 0);
      }
      process(s0v, row_lo, t == ip, m0r, o0, l0, kk0, vf);
    }

    __syncthreads();
    cur ^= 1;
  }

  {
    float inv0 = 1.0f / l0[0], inv1 = 1.0f / l1[0];
#pragma unroll
    for (int db = 0; db < 4; ++db) {
      ushort4 w0, w1;
      w0.x = f2b(o0[db][0] * inv0); w0.y = f2b(o0[db][1] * inv0);
      w0.z = f2b(o0[db][2] * inv0); w0.w = f2b(o0[db][3] * inv0);
      w1.x = f2b(o1[db][0] * inv1); w1.y = f2b(o1[db][1] * inv1);
      w1.z = f2b(o1[db][2] * inv1); w1.w = f2b(o1[db][3] * inv1);
      *(ushort4*)&Ob[base + (size_t)row_lo * E_DIM + db * 16 + lg * 4] = w0;
      *(ushort4*)&Ob[base + (size_t)row_hi * E_DIM + db * 16 + lg * 4] = w1;
    }
  }
}

extern "C" void kernel_launch(void* const* d_in, const int* in_sizes, int n_in,
                              void* d_out, int out_size, void* d_ws, size_t ws_size,
                              hipStream_t stream) {
  const float* x    = (const float*)d_in[0];
  const float* wq_w = (const float*)d_in[1];
  const float* wq_b = (const float*)d_in[2];
  const float* wk_w = (const float*)d_in[3];
  const float* wk_b = (const float*)d_in[4];
  const float* wv_w = (const float*)d_in[5];
  const float* wv_b = (const float*)d_in[6];
  const float* wo_w = (const float*)d_in[7];
  const float* wo_b = (const float*)d_in[8];
  float* out = (float*)d_out;

  const size_t XE = (size_t)M_ROWS * E_DIM;
  const size_t WE = (size_t)E_DIM * E_DIM;
  char* ws = (char*)d_ws;
  unsigned short* xb    = (unsigned short*)ws; ws += XE * 2;
  unsigned short* wqkvT = (unsigned short*)ws; ws += 3 * WE * 2;  // [3072][1024]
  unsigned short* woT   = (unsigned short*)ws; ws += WE * 2;
  unsigned short* Qb    = (unsigned short*)ws; ws += XE * 2;
  unsigned short* Kb    = (unsigned short*)ws; ws += XE * 2;
  unsigned short* Vt    = (unsigned short*)ws; ws += XE * 2;  // [bh*64+d][s]
  unsigned short* Ao    = (unsigned short*)ws; ws += XE * 2;

  cast_x_kernel<<<2048, 256, 0, stream>>>(x, xb, (int)(XE / 4));
  wtrans4_kernel<<<dim3(E_DIM / 64, E_DIM / 64, 4), 256, 0, stream>>>(
      wq_w, wk_w, wv_w, wo_w, wqkvT, wqkvT + WE, wqkvT + 2 * WE, woT);

  gemm_qkv<<<dim3(M_ROWS / 128, 3072 / 128), 256, 0, stream>>>(
      xb, wqkvT, wq_b, wk_b, wv_b, Qb, Kb, Vt);

  attn8_kernel<<<1024, 256, 0, stream>>>(Qb, Kb, Vt, Ao);

  gemm_out<<<dim3(M_ROWS / 128, E_DIM / 128), 256, 0, stream>>>(Ao, woT, wo_b, out);
}

// Round 11
// 224.514 us; speedup vs baseline: 1.5362x; 1.5362x over previous
//
#include <hip/hip_runtime.h>
#include <hip/hip_bf16.h>

// Problem constants (CausalMultiHeadSelfAttention): B=4, S=2048, E=1024, H=16, D=64
#define E_DIM 1024
#define N_HEADS 16
#define HEAD_D 64
#define BATCH 4
#define SEQ 2048
#define M_ROWS (BATCH * SEQ)  // 8192
#define SCALE2 0.1803368801111244f  // 0.125 * log2(e): folded into Q at projection

typedef __attribute__((ext_vector_type(4))) float f32x4;
typedef __attribute__((ext_vector_type(8))) short s16x8;  // 8 bf16 in 4 VGPRs
typedef unsigned uint2v __attribute__((ext_vector_type(2)));

__device__ __forceinline__ unsigned short f2b(float f) {
  union { float f; unsigned u; } v; v.f = f;
  unsigned r = v.u + 0x7fffu + ((v.u >> 16) & 1u);  // RNE
  return (unsigned short)(r >> 16);
}

__device__ __forceinline__ unsigned packbf2(float lo, float hi) {
  union { __hip_bfloat162 h; unsigned u; } p;
  p.h = __float22bfloat162_rn(float2{lo, hi});  // v_cvt_pk_bf16_f32
  return p.u;
}

__device__ __forceinline__ void gld16(const void* g, void* l) {
  __builtin_amdgcn_global_load_lds(
      (__attribute__((address_space(1))) void*)(g),
      (__attribute__((address_space(3))) void*)(l), 16, 0, 0);
}

// lane-bit5 <-> reg swap (T12)
__device__ __forceinline__ void swap32(unsigned& a, unsigned& b, bool hi5) {
#if __has_builtin(__builtin_amdgcn_permlane32_swap)
  uint2v r = __builtin_amdgcn_permlane32_swap(a, b, false, false);
  a = r[0]; b = r[1];
#else
  unsigned x = hi5 ? a : b;
  x = __shfl_xor(x, 32, 64);
  unsigned na = hi5 ? x : a;
  b = hi5 ? b : x;
  a = na;
#endif
}
// lane-bit4 <-> reg swap
__device__ __forceinline__ void swap16(unsigned& a, unsigned& b, bool hi4) {
#if __has_builtin(__builtin_amdgcn_permlane16_swap)
  uint2v r = __builtin_amdgcn_permlane16_swap(a, b, false, false);
  a = r[0]; b = r[1];
#else
  unsigned x = hi4 ? a : b;
  x = __shfl_xor(x, 16, 64);
  unsigned na = hi4 ? x : a;
  b = hi4 ? b : x;
  a = na;
#endif
}

// ---------------- cast x (fp32 -> bf16), vectorized ----------------
__global__ __launch_bounds__(256) void cast_x_kernel(const float* __restrict__ in,
                                                     unsigned short* __restrict__ out,
                                                     int n4) {
  int i = blockIdx.x * 256 + threadIdx.x;
  const int stride = gridDim.x * 256;
  for (; i < n4; i += stride) {
    float4 v = ((const float4*)in)[i];
    ushort4 o;
    o.x = f2b(v.x); o.y = f2b(v.y); o.z = f2b(v.z); o.w = f2b(v.w);
    ((ushort4*)out)[i] = o;
  }
}

// ------- fused weight transpose+cast: 4 weights in one launch (grid.z) -------
__global__ __launch_bounds__(256) void wtrans4_kernel(const float* __restrict__ W0,
                                                      const float* __restrict__ W1,
                                                      const float* __restrict__ W2,
                                                      const float* __restrict__ W3,
                                                      unsigned short* __restrict__ D0,
                                                      unsigned short* __restrict__ D1,
                                                      unsigned short* __restrict__ D2,
                                                      unsigned short* __restrict__ D3) {
  const int z = blockIdx.z;
  const float* W = (z == 0) ? W0 : (z == 1) ? W1 : (z == 2) ? W2 : W3;
  unsigned short* WT = (z == 0) ? D0 : (z == 1) ? D1 : (z == 2) ? D2 : D3;
  __shared__ float t[64][65];
  const int k0 = blockIdx.x * 64, n0 = blockIdx.y * 64;
  const int tid = threadIdx.x;
  const int rr = tid >> 4, cc = (tid & 15) * 4;
  for (int p = 0; p < 4; ++p) {
    int row = p * 16 + rr;
    float4 v = *(const float4*)&W[(size_t)(k0 + row) * E_DIM + n0 + cc];
    t[row][cc] = v.x; t[row][cc + 1] = v.y; t[row][cc + 2] = v.z; t[row][cc + 3] = v.w;
  }
  __syncthreads();
  for (int p = 0; p < 4; ++p) {
    int nrow = p * 16 + rr;
    ushort4 o;
    o.x = f2b(t[cc][nrow]); o.y = f2b(t[cc + 1][nrow]);
    o.z = f2b(t[cc + 2][nrow]); o.w = f2b(t[cc + 3][nrow]);
    *(ushort4*)&WT[(size_t)(n0 + nrow) * E_DIM + k0 + cc] = o;
  }
}

// ---------------- fused QKV GEMM: 128x128 tile (round-8 config, 2 blocks/CU) ----------------
// Double-buffered LDS, issue-early staging, T2 XOR swizzle, Q pre-scaled.
// NEW (T1): bijective XCD swizzle on a 1-D grid (1536 blocks, 1536%8==0):
// each XCD owns 3 contiguous n-panels -> 768KB of W resident in its L2,
// A panels stream once instead of being replicated across 8 L2s.
__global__ __launch_bounds__(256) void gemm_qkv(const unsigned short* __restrict__ A,
                                                const unsigned short* __restrict__ BT,
                                                const float* __restrict__ bq,
                                                const float* __restrict__ bk,
                                                const float* __restrict__ bv,
                                                unsigned short* __restrict__ Qb,
                                                unsigned short* __restrict__ Kb,
                                                unsigned short* __restrict__ Vt) {
  __shared__ unsigned short Al[2][8192];
  __shared__ unsigned short Bl[2][8192];
  const int K = E_DIM;
  const int tid = threadIdx.x;
  const int lane = tid & 63;
  const int wave = tid >> 6;
  const int wr = wave >> 1, wc = wave & 1;
  // XCD swizzle: 1536 blocks = 8 xcd * 192; within an XCD m varies fastest
  const int id = blockIdx.x;
  const int swz_id = (id & 7) * 192 + (id >> 3);
  const int m0 = (swz_id & 63) << 7;   // 64 m-panels
  const int n0 = (swz_id >> 6) << 7;   // 24 n-panels
  const int lrow = lane & 15, lg = lane >> 4;

  f32x4 acc[4][4] = {};

  const int ob = tid << 4;
  const int dstb = (wave << 10);
  int srow[4], scol[4];
#pragma unroll
  for (int p = 0; p < 4; ++p) {
    int o = p * 4096 + ob;
    srow[p] = o >> 7;
    scol[p] = ((o ^ ((srow[p] & 7) << 4)) & 127) >> 1;
  }

  auto stage = [&](int buf, int k0) {
#pragma unroll
    for (int p = 0; p < 4; ++p) {
      gld16((const void*)(A + (size_t)(m0 + srow[p]) * K + k0 + scol[p]),
            (void*)((char*)&Al[buf][0] + p * 4096 + dstb));
      gld16((const void*)(BT + (size_t)(n0 + srow[p]) * K + k0 + scol[p]),
            (void*)((char*)&Bl[buf][0] + p * 4096 + dstb));
    }
  };

  const int swz = (lrow & 7) << 4;

  stage(0, 0);
  __syncthreads();
  int cur = 0;
  const int nt = K / 64;

  for (int t = 0; t < nt; ++t) {
    if (t + 1 < nt) stage(cur ^ 1, (t + 1) * 64);
    const char* Ac = (const char*)&Al[cur][0];
    const char* Bc = (const char*)&Bl[cur][0];
#pragma unroll
    for (int ks = 0; ks < 2; ++ks) {
      const int cb = ks * 64 + lg * 16;
      s16x8 af[4], bf_[4];
#pragma unroll
      for (int i = 0; i < 4; ++i)
        af[i] = *(const s16x8*)(Ac + (((wr * 64 + i * 16 + lrow) * 128 + cb) ^ swz));
#pragma unroll
      for (int j = 0; j < 4; ++j)
        bf_[j] = *(const s16x8*)(Bc + (((wc * 64 + j * 16 + lrow) * 128 + cb) ^ swz));
#pragma unroll
      for (int i = 0; i < 4; ++i)
#pragma unroll
        for (int j = 0; j < 4; ++j)
          acc[i][j] = __builtin_amdgcn_mfma_f32_16x16x32_bf16(af[i], bf_[j], acc[i][j], 0, 0, 0);
    }
    __syncthreads();
    cur ^= 1;
  }

  for (int j = 0; j < 4; ++j) {
    int c = n0 + wc * 64 + j * 16 + lrow;   // global col in [0,3072)
    int proj = c >> 10, cc = c & 1023;
    float bvl = (proj == 0) ? bq[cc] : (proj == 1) ? bk[cc] : bv[cc];
    for (int i = 0; i < 4; ++i) {
      int r0 = m0 + wr * 64 + i * 16 + (lg << 2);
      for (int r = 0; r < 4; ++r) {
        float val = acc[i][j][r] + bvl;
        int m = r0 + r;
        if (proj == 0) {
          Qb[(size_t)m * E_DIM + cc] = f2b(val * SCALE2);  // pre-scaled Q
        } else if (proj == 1) {
          Kb[(size_t)m * E_DIM + cc] = f2b(val);
        } else {
          int b = m >> 11, s = m & 2047;
          int h = cc >> 6, d = cc & 63;
          Vt[((size_t)((b * 16 + h) * 64 + d)) * SEQ + s] = f2b(val);
        }
      }
    }
  }
}

// ---------------- output projection GEMM (f32 out), round-8 config + T1 swizzle ----------------
__global__ __launch_bounds__(256) void gemm_out(const unsigned short* __restrict__ A,
                                                const unsigned short* __restrict__ BT,
                                                const float* __restrict__ bias,
                                                float* __restrict__ C) {
  __shared__ unsigned short Al[2][8192];
  __shared__ unsigned short Bl[2][8192];
  const int K = E_DIM, N = E_DIM;
  const int tid = threadIdx.x;
  const int lane = tid & 63;
  const int wave = tid >> 6;
  const int wr = wave >> 1, wc = wave & 1;
  // XCD swizzle: 512 blocks = 8 xcd * 64; each XCD owns one n-panel
  const int id = blockIdx.x;
  const int swz_id = (id & 7) * 64 + (id >> 3);
  const int m0 = (swz_id & 63) << 7;   // 64 m-panels
  const int n0 = (swz_id >> 6) << 7;   // 8 n-panels
  const int lrow = lane & 15, lg = lane >> 4;

  f32x4 acc[4][4] = {};

  const int ob = tid << 4;
  const int dstb = (wave << 10);
  int srow[4], scol[4];
#pragma unroll
  for (int p = 0; p < 4; ++p) {
    int o = p * 4096 + ob;
    srow[p] = o >> 7;
    scol[p] = ((o ^ ((srow[p] & 7) << 4)) & 127) >> 1;
  }

  auto stage = [&](int buf, int k0) {
#pragma unroll
    for (int p = 0; p < 4; ++p) {
      gld16((const void*)(A + (size_t)(m0 + srow[p]) * K + k0 + scol[p]),
            (void*)((char*)&Al[buf][0] + p * 4096 + dstb));
      gld16((const void*)(BT + (size_t)(n0 + srow[p]) * K + k0 + scol[p]),
            (void*)((char*)&Bl[buf][0] + p * 4096 + dstb));
    }
  };

  const int swz = (lrow & 7) << 4;

  stage(0, 0);
  __syncthreads();
  int cur = 0;
  const int nt = K / 64;

  for (int t = 0; t < nt; ++t) {
    if (t + 1 < nt) stage(cur ^ 1, (t + 1) * 64);
    const char* Ac = (const char*)&Al[cur][0];
    const char* Bc = (const char*)&Bl[cur][0];
#pragma unroll
    for (int ks = 0; ks < 2; ++ks) {
      const int cb = ks * 64 + lg * 16;
      s16x8 af[4], bf_[4];
#pragma unroll
      for (int i = 0; i < 4; ++i)
        af[i] = *(const s16x8*)(Ac + (((wr * 64 + i * 16 + lrow) * 128 + cb) ^ swz));
#pragma unroll
      for (int j = 0; j < 4; ++j)
        bf_[j] = *(const s16x8*)(Bc + (((wc * 64 + j * 16 + lrow) * 128 + cb) ^ swz));
#pragma unroll
      for (int i = 0; i < 4; ++i)
#pragma unroll
        for (int j = 0; j < 4; ++j)
          acc[i][j] = __builtin_amdgcn_mfma_f32_16x16x32_bf16(af[i], bf_[j], acc[i][j], 0, 0, 0);
    }
    __syncthreads();
    cur ^= 1;
  }

  for (int j = 0; j < 4; ++j) {
    int col = n0 + wc * 64 + j * 16 + lrow;
    float bvl = bias[col];
    for (int i = 0; i < 4; ++i) {
      int r0 = m0 + wr * 64 + i * 16 + (lg << 2);
      for (int r = 0; r < 4; ++r)
        C[(size_t)(r0 + r) * N + col] = acc[i][j][r] + bvl;
    }
  }
}

// ---------------- causal flash attention v7 (round-8 config: (256,2), VGPR=84, no spill) ----------------
__global__ __launch_bounds__(256, 2) void attn7_kernel(const unsigned short* __restrict__ Qb,
                                                       const unsigned short* __restrict__ Kb,
                                                       const unsigned short* __restrict__ Vt,
                                                       unsigned short* __restrict__ Ob) {
  __shared__ unsigned short Kl[2][4096];
  __shared__ unsigned short Vl[2][4096];

  const int tid = threadIdx.x, lane = tid & 63, wave = tid >> 6;
  const int id = blockIdx.x;
  const int xcd = id & 7;
  const int slot = id >> 3;
  const int bh = (xcd << 3) | (slot >> 4);
  const int ip = slot & 15;
  const size_t base = (size_t)(bh >> 4) * SEQ * E_DIM + (size_t)(bh & 15) * HEAD_D;
  const size_t baset = (size_t)bh * HEAD_D * SEQ;
  const int lq = lane & 15, lg = lane >> 4;

  const int row_lo = ip * 64 + wave * 16 + lq;
  const int row_hi = (31 - ip) * 64 + wave * 16 + lq;

  s16x8 qf0[2], qf1[2];
  {
    const unsigned short* p0 = Qb + base + (size_t)row_lo * E_DIM + lg * 8;
    qf0[0] = *(const s16x8*)p0; qf0[1] = *(const s16x8*)(p0 + 32);
    const unsigned short* p1 = Qb + base + (size_t)row_hi * E_DIM + lg * 8;
    qf1[0] = *(const s16x8*)p1; qf1[1] = *(const s16x8*)(p1 + 32);
  }

  const short onebf = (short)0x3F80;
  const s16x8 ones = {onebf, onebf, onebf, onebf, onebf, onebf, onebf, onebf};

  float m0r = -1e30f, m1r = -1e30f;
  f32x4 o0[4] = {}, o1[4] = {};
  f32x4 l0 = {}, l1 = {};
  const int ntm1 = 31 - ip;
  const bool hi5 = (lane & 32) != 0, hi4 = (lane & 16) != 0;

  const int o0b = tid << 4;
  const int o1b = 4096 + (tid << 4);
  const int r0s = o0b >> 7, r1s = o1b >> 7;
  const int c0s = ((o0b ^ ((r0s & 7) << 4)) & 127) >> 1;
  const int c1s = ((o1b ^ ((r1s & 7) << 4)) & 127) >> 1;
  const int dst0 = wave << 10;
  const int dst1 = 4096 + (wave << 10);

  auto stage = [&](int buf, int k0) {
    gld16((const void*)(Kb + base + (size_t)(k0 + r0s) * E_DIM + c0s),
          (void*)((char*)&Kl[buf][0] + dst0));
    gld16((const void*)(Kb + base + (size_t)(k0 + r1s) * E_DIM + c1s),
          (void*)((char*)&Kl[buf][0] + dst1));
    gld16((const void*)(Vt + baset + (size_t)r0s * SEQ + k0 + c0s),
          (void*)((char*)&Vl[buf][0] + dst0));
    gld16((const void*)(Vt + baset + (size_t)r1s * SEQ + k0 + c1s),
          (void*)((char*)&Vl[buf][0] + dst1));
  };

  const int swz = (lq & 7) << 4;

  auto process = [&](f32x4 (&sv)[4], int qrow, bool diag, float& mreg,
                     f32x4 (&oacc)[4], f32x4& lacc, int kk0, s16x8 (&vf)[4][2]) {
    if (diag) {
#pragma unroll
      for (int kb = 0; kb < 4; ++kb)
#pragma unroll
        for (int r = 0; r < 4; ++r) {
          int kk = kk0 + kb * 16 + lg * 4 + r;
          if (kk > qrow) sv[kb][r] = -1e30f;
        }
    }
    float t0, t1, mk[4];
#pragma unroll
    for (int kb = 0; kb < 4; ++kb) {
      t0 = fmaxf(sv[kb][0], sv[kb][1]);
      t1 = fmaxf(sv[kb][2], sv[kb][3]);
      mk[kb] = fmaxf(t0, t1);
    }
    float mx = fmaxf(fmaxf(mk[0], mk[1]), fmaxf(mk[2], mk[3]));
    mx = fmaxf(mx, __shfl_xor(mx, 16, 64));
    mx = fmaxf(mx, __shfl_xor(mx, 32, 64));
    if (!__all(mx - mreg <= 8.0f)) {
      float mn = fmaxf(mreg, mx);
      float corr = __builtin_amdgcn_exp2f(mreg - mn);
#pragma unroll
      for (int db = 0; db < 4; ++db) oacc[db] = oacc[db] * corr;
      lacc = lacc * corr;
      mreg = mn;
    }
    const float mn = mreg;
    unsigned c[4][2];
#pragma unroll
    for (int kb = 0; kb < 4; ++kb)
#pragma unroll
      for (int rp = 0; rp < 2; ++rp) {
        float plo = __builtin_amdgcn_exp2f(sv[kb][2 * rp] - mn);
        float phi = __builtin_amdgcn_exp2f(sv[kb][2 * rp + 1] - mn);
        c[kb][rp] = packbf2(plo, phi);
      }
#pragma unroll
    for (int k1 = 0; k1 < 2; ++k1)
#pragma unroll
      for (int rp = 0; rp < 2; ++rp)
        swap32(c[2 * k1][rp], c[2 * k1 + 1][rp], hi5);
#pragma unroll
    for (int k1 = 0; k1 < 2; ++k1)
#pragma unroll
      for (int rp = 0; rp < 2; ++rp)
        swap16(c[2 * k1][rp], c[2 * k1 + 1][rp], hi4);
#pragma unroll
    for (int ks = 0; ks < 2; ++ks) {
      union { unsigned w[4]; s16x8 v; } pu;
      pu.w[0] = c[2 * ks][0]; pu.w[1] = c[2 * ks][1];
      pu.w[2] = c[2 * ks + 1][0]; pu.w[3] = c[2 * ks + 1][1];
      lacc = __builtin_amdgcn_mfma_f32_16x16x32_bf16(ones, pu.v, lacc, 0, 0, 0);
#pragma unroll
      for (int db = 0; db < 4; ++db)
        oacc[db] = __builtin_amdgcn_mfma_f32_16x16x32_bf16(vf[db][ks], pu.v, oacc[db], 0, 0, 0);
    }
  };

  stage(0, 0);
  __syncthreads();
  int cur = 0;

  for (int t = 0; t <= ntm1; ++t) {
    if (t < ntm1) stage(cur ^ 1, (t + 1) * 64);

    const char* Kc = (const char*)&Kl[cur][0];
    const char* Vc = (const char*)&Vl[cur][0];
    s16x8 kf[4][2];
#pragma unroll
    for (int kb = 0; kb < 4; ++kb)
#pragma unroll
      for (int j = 0; j < 2; ++j)
        kf[kb][j] = *(const s16x8*)(Kc + (((kb * 16 + lq) * 128 + j * 64 + lg * 16) ^ swz));
    s16x8 vf[4][2];
#pragma unroll
    for (int db = 0; db < 4; ++db)
#pragma unroll
      for (int ks = 0; ks < 2; ++ks)
        vf[db][ks] = *(const s16x8*)(Vc + (((db * 16 + lq) * 128 + ks * 64 + lg * 16) ^ swz));

    const int kk0 = t * 64;
    {
      f32x4 s1v[4] = {};
#pragma unroll
      for (int kb = 0; kb < 4; ++kb) {
        s1v[kb] = __builtin_amdgcn_mfma_f32_16x16x32_bf16(kf[kb][0], qf1[0], s1v[kb], 0, 0, 0);
        s1v[kb] = __builtin_amdgcn_mfma_f32_16x16x32_bf16(kf[kb][1], qf1[1], s1v[kb], 0, 0, 0);
      }
      process(s1v, row_hi, t == ntm1, m1r, o1, l1, kk0, vf);
    }
    if (t <= ip) {
      f32x4 s0v[4] = {};
#pragma unroll
      for (int kb = 0; kb < 4; ++kb) {
        s0v[kb] = __builtin_amdgcn_mfma_f32_16x16x32_bf16(kf[kb][0], qf0[0], s0v[kb], 0, 0, 0);
        s0v[kb] = __builtin_amdgcn_mfma_f32_16x16x32_bf16(kf[kb][1], qf0[1], s0v[kb], 0, 0, 0);
      }
      process(s0v, row_lo, t == ip, m0r, o0, l0, kk0, vf);
    }

    __syncthreads();
    cur ^= 1;
  }

  {
    float inv0 = 1.0f / l0[0], inv1 = 1.0f / l1[0];
#pragma unroll
    for (int db = 0; db < 4; ++db) {
      ushort4 w0, w1;
      w0.x = f2b(o0[db][0] * inv0); w0.y = f2b(o0[db][1] * inv0);
      w0.z = f2b(o0[db][2] * inv0); w0.w = f2b(o0[db][3] * inv0);
      w1.x = f2b(o1[db][0] * inv1); w1.y = f2b(o1[db][1] * inv1);
      w1.z = f2b(o1[db][2] * inv1); w1.w = f2b(o1[db][3] * inv1);
      *(ushort4*)&Ob[base + (size_t)row_lo * E_DIM + db * 16 + lg * 4] = w0;
      *(ushort4*)&Ob[base + (size_t)row_hi * E_DIM + db * 16 + lg * 4] = w1;
    }
  }
}

extern "C" void kernel_launch(void* const* d_in, const int* in_sizes, int n_in,
                              void* d_out, int out_size, void* d_ws, size_t ws_size,
                              hipStream_t stream) {
  const float* x    = (const float*)d_in[0];
  const float* wq_w = (const float*)d_in[1];
  const float* wq_b = (const float*)d_in[2];
  const float* wk_w = (const float*)d_in[3];
  const float* wk_b = (const float*)d_in[4];
  const float* wv_w = (const float*)d_in[5];
  const float* wv_b = (const float*)d_in[6];
  const float* wo_w = (const float*)d_in[7];
  const float* wo_b = (const float*)d_in[8];
  float* out = (float*)d_out;

  const size_t XE = (size_t)M_ROWS * E_DIM;
  const size_t WE = (size_t)E_DIM * E_DIM;
  char* ws = (char*)d_ws;
  unsigned short* xb    = (unsigned short*)ws; ws += XE * 2;
  unsigned short* wqkvT = (unsigned short*)ws; ws += 3 * WE * 2;  // [3072][1024]
  unsigned short* woT   = (unsigned short*)ws; ws += WE * 2;
  unsigned short* Qb    = (unsigned short*)ws; ws += XE * 2;
  unsigned short* Kb    = (unsigned short*)ws; ws += XE * 2;
  unsigned short* Vt    = (unsigned short*)ws; ws += XE * 2;  // [bh*64+d][s]
  unsigned short* Ao    = (unsigned short*)ws; ws += XE * 2;

  cast_x_kernel<<<2048, 256, 0, stream>>>(x, xb, (int)(XE / 4));
  wtrans4_kernel<<<dim3(E_DIM / 64, E_DIM / 64, 4), 256, 0, stream>>>(
      wq_w, wk_w, wv_w, wo_w, wqkvT, wqkvT + WE, wqkvT + 2 * WE, woT);

  gemm_qkv<<<1536, 256, 0, stream>>>(xb, wqkvT, wq_b, wk_b, wv_b, Qb, Kb, Vt);

  attn7_kernel<<<1024, 256, 0, stream>>>(Qb, Kb, Vt, Ao);

  gemm_out<<<512, 256, 0, stream>>>(Ao, woT, wo_b, out);
}

// Round 12
// 200.493 us; speedup vs baseline: 1.7202x; 1.1198x over previous
//
#include <hip/hip_runtime.h>
#include <hip/hip_bf16.h>

// Problem constants (CausalMultiHeadSelfAttention): B=4, S=2048, E=1024, H=16, D=64
#define E_DIM 1024
#define N_HEADS 16
#define HEAD_D 64
#define BATCH 4
#define SEQ 2048
#define M_ROWS (BATCH * SEQ)  // 8192
#define SCALE2 0.1803368801111244f  // 0.125 * log2(e): folded into Q at projection

typedef __attribute__((ext_vector_type(4))) float f32x4;
typedef __attribute__((ext_vector_type(8))) short s16x8;  // 8 bf16 in 4 VGPRs
typedef unsigned uint2v __attribute__((ext_vector_type(2)));

__device__ __forceinline__ unsigned short f2b(float f) {
  union { float f; unsigned u; } v; v.f = f;
  unsigned r = v.u + 0x7fffu + ((v.u >> 16) & 1u);  // RNE
  return (unsigned short)(r >> 16);
}

__device__ __forceinline__ unsigned packbf2(float lo, float hi) {
  union { __hip_bfloat162 h; unsigned u; } p;
  p.h = __float22bfloat162_rn(float2{lo, hi});  // v_cvt_pk_bf16_f32
  return p.u;
}

__device__ __forceinline__ void gld16(const void* g, void* l) {
  __builtin_amdgcn_global_load_lds(
      (__attribute__((address_space(1))) void*)(g),
      (__attribute__((address_space(3))) void*)(l), 16, 0, 0);
}

// lane-bit5 <-> reg swap (T12)
__device__ __forceinline__ void swap32(unsigned& a, unsigned& b, bool hi5) {
#if __has_builtin(__builtin_amdgcn_permlane32_swap)
  uint2v r = __builtin_amdgcn_permlane32_swap(a, b, false, false);
  a = r[0]; b = r[1];
#else
  unsigned x = hi5 ? a : b;
  x = __shfl_xor(x, 32, 64);
  unsigned na = hi5 ? x : a;
  b = hi5 ? b : x;
  a = na;
#endif
}
// lane-bit4 <-> reg swap
__device__ __forceinline__ void swap16(unsigned& a, unsigned& b, bool hi4) {
#if __has_builtin(__builtin_amdgcn_permlane16_swap)
  uint2v r = __builtin_amdgcn_permlane16_swap(a, b, false, false);
  a = r[0]; b = r[1];
#else
  unsigned x = hi4 ? a : b;
  x = __shfl_xor(x, 16, 64);
  unsigned na = hi4 ? x : a;
  b = hi4 ? b : x;
  a = na;
#endif
}

// ---------------- cast x (fp32 -> bf16), vectorized ----------------
__global__ __launch_bounds__(256) void cast_x_kernel(const float* __restrict__ in,
                                                     unsigned short* __restrict__ out,
                                                     int n4) {
  int i = blockIdx.x * 256 + threadIdx.x;
  const int stride = gridDim.x * 256;
  for (; i < n4; i += stride) {
    float4 v = ((const float4*)in)[i];
    ushort4 o;
    o.x = f2b(v.x); o.y = f2b(v.y); o.z = f2b(v.z); o.w = f2b(v.w);
    ((ushort4*)out)[i] = o;
  }
}

// ------- fused weight transpose+cast: 4 weights in one launch (grid.z) -------
__global__ __launch_bounds__(256) void wtrans4_kernel(const float* __restrict__ W0,
                                                      const float* __restrict__ W1,
                                                      const float* __restrict__ W2,
                                                      const float* __restrict__ W3,
                                                      unsigned short* __restrict__ D0,
                                                      unsigned short* __restrict__ D1,
                                                      unsigned short* __restrict__ D2,
                                                      unsigned short* __restrict__ D3) {
  const int z = blockIdx.z;
  const float* W = (z == 0) ? W0 : (z == 1) ? W1 : (z == 2) ? W2 : W3;
  unsigned short* WT = (z == 0) ? D0 : (z == 1) ? D1 : (z == 2) ? D2 : D3;
  __shared__ float t[64][65];
  const int k0 = blockIdx.x * 64, n0 = blockIdx.y * 64;
  const int tid = threadIdx.x;
  const int rr = tid >> 4, cc = (tid & 15) * 4;
  for (int p = 0; p < 4; ++p) {
    int row = p * 16 + rr;
    float4 v = *(const float4*)&W[(size_t)(k0 + row) * E_DIM + n0 + cc];
    t[row][cc] = v.x; t[row][cc + 1] = v.y; t[row][cc + 2] = v.z; t[row][cc + 3] = v.w;
  }
  __syncthreads();
  for (int p = 0; p < 4; ++p) {
    int nrow = p * 16 + rr;
    ushort4 o;
    o.x = f2b(t[cc][nrow]); o.y = f2b(t[cc + 1][nrow]);
    o.z = f2b(t[cc + 2][nrow]); o.w = f2b(t[cc + 3][nrow]);
    *(ushort4*)&WT[(size_t)(n0 + nrow) * E_DIM + k0 + cc] = o;
  }
}

// ---------------- fused QKV GEMM: 128x128 tile (verified round-8 config) ----------------
// Double-buffered LDS, issue-early staging, T2 XOR swizzle, 2 blocks/CU,
// 2-D grid (m fastest -> chip-wide n-panel sync = best L2/L3 behavior;
// round-11 lesson: XCD n-partitioning quadruples FETCH). Q pre-scaled.
__global__ __launch_bounds__(256) void gemm_qkv(const unsigned short* __restrict__ A,
                                                const unsigned short* __restrict__ BT,
                                                const float* __restrict__ bq,
                                                const float* __restrict__ bk,
                                                const float* __restrict__ bv,
                                                unsigned short* __restrict__ Qb,
                                                unsigned short* __restrict__ Kb,
                                                unsigned short* __restrict__ Vt) {
  __shared__ unsigned short Al[2][8192];
  __shared__ unsigned short Bl[2][8192];
  const int K = E_DIM;
  const int tid = threadIdx.x;
  const int lane = tid & 63;
  const int wave = tid >> 6;
  const int wr = wave >> 1, wc = wave & 1;
  const int m0 = blockIdx.x * 128, n0 = blockIdx.y * 128;
  const int lrow = lane & 15, lg = lane >> 4;

  f32x4 acc[4][4] = {};

  const int ob = tid << 4;
  const int dstb = (wave << 10);
  int srow[4], scol[4];
#pragma unroll
  for (int p = 0; p < 4; ++p) {
    int o = p * 4096 + ob;
    srow[p] = o >> 7;
    scol[p] = ((o ^ ((srow[p] & 7) << 4)) & 127) >> 1;
  }

  auto stage = [&](int buf, int k0) {
#pragma unroll
    for (int p = 0; p < 4; ++p) {
      gld16((const void*)(A + (size_t)(m0 + srow[p]) * K + k0 + scol[p]),
            (void*)((char*)&Al[buf][0] + p * 4096 + dstb));
      gld16((const void*)(BT + (size_t)(n0 + srow[p]) * K + k0 + scol[p]),
            (void*)((char*)&Bl[buf][0] + p * 4096 + dstb));
    }
  };

  const int swz = (lrow & 7) << 4;

  stage(0, 0);
  __syncthreads();
  int cur = 0;
  const int nt = K / 64;

  for (int t = 0; t < nt; ++t) {
    if (t + 1 < nt) stage(cur ^ 1, (t + 1) * 64);
    const char* Ac = (const char*)&Al[cur][0];
    const char* Bc = (const char*)&Bl[cur][0];
#pragma unroll
    for (int ks = 0; ks < 2; ++ks) {
      const int cb = ks * 64 + lg * 16;
      s16x8 af[4], bf_[4];
#pragma unroll
      for (int i = 0; i < 4; ++i)
        af[i] = *(const s16x8*)(Ac + (((wr * 64 + i * 16 + lrow) * 128 + cb) ^ swz));
#pragma unroll
      for (int j = 0; j < 4; ++j)
        bf_[j] = *(const s16x8*)(Bc + (((wc * 64 + j * 16 + lrow) * 128 + cb) ^ swz));
#pragma unroll
      for (int i = 0; i < 4; ++i)
#pragma unroll
        for (int j = 0; j < 4; ++j)
          acc[i][j] = __builtin_amdgcn_mfma_f32_16x16x32_bf16(af[i], bf_[j], acc[i][j], 0, 0, 0);
    }
    __syncthreads();
    cur ^= 1;
  }

  for (int j = 0; j < 4; ++j) {
    int c = n0 + wc * 64 + j * 16 + lrow;   // global col in [0,3072)
    int proj = c >> 10, cc = c & 1023;
    float bvl = (proj == 0) ? bq[cc] : (proj == 1) ? bk[cc] : bv[cc];
    for (int i = 0; i < 4; ++i) {
      int r0 = m0 + wr * 64 + i * 16 + (lg << 2);
      for (int r = 0; r < 4; ++r) {
        float val = acc[i][j][r] + bvl;
        int m = r0 + r;
        if (proj == 0) {
          Qb[(size_t)m * E_DIM + cc] = f2b(val * SCALE2);  // pre-scaled Q
        } else if (proj == 1) {
          Kb[(size_t)m * E_DIM + cc] = f2b(val);
        } else {
          int b = m >> 11, s = m & 2047;
          int h = cc >> 6, d = cc & 63;
          Vt[((size_t)((b * 16 + h) * 64 + d)) * SEQ + s] = f2b(val);
        }
      }
    }
  }
}

// ---------------- output projection GEMM (f32 out), verified round-8 config ----------------
__global__ __launch_bounds__(256) void gemm_out(const unsigned short* __restrict__ A,
                                                const unsigned short* __restrict__ BT,
                                                const float* __restrict__ bias,
                                                float* __restrict__ C) {
  __shared__ unsigned short Al[2][8192];
  __shared__ unsigned short Bl[2][8192];
  const int K = E_DIM, N = E_DIM;
  const int tid = threadIdx.x;
  const int lane = tid & 63;
  const int wave = tid >> 6;
  const int wr = wave >> 1, wc = wave & 1;
  const int m0 = blockIdx.x * 128, n0 = blockIdx.y * 128;
  const int lrow = lane & 15, lg = lane >> 4;

  f32x4 acc[4][4] = {};

  const int ob = tid << 4;
  const int dstb = (wave << 10);
  int srow[4], scol[4];
#pragma unroll
  for (int p = 0; p < 4; ++p) {
    int o = p * 4096 + ob;
    srow[p] = o >> 7;
    scol[p] = ((o ^ ((srow[p] & 7) << 4)) & 127) >> 1;
  }

  auto stage = [&](int buf, int k0) {
#pragma unroll
    for (int p = 0; p < 4; ++p) {
      gld16((const void*)(A + (size_t)(m0 + srow[p]) * K + k0 + scol[p]),
            (void*)((char*)&Al[buf][0] + p * 4096 + dstb));
      gld16((const void*)(BT + (size_t)(n0 + srow[p]) * K + k0 + scol[p]),
            (void*)((char*)&Bl[buf][0] + p * 4096 + dstb));
    }
  };

  const int swz = (lrow & 7) << 4;

  stage(0, 0);
  __syncthreads();
  int cur = 0;
  const int nt = K / 64;

  for (int t = 0; t < nt; ++t) {
    if (t + 1 < nt) stage(cur ^ 1, (t + 1) * 64);
    const char* Ac = (const char*)&Al[cur][0];
    const char* Bc = (const char*)&Bl[cur][0];
#pragma unroll
    for (int ks = 0; ks < 2; ++ks) {
      const int cb = ks * 64 + lg * 16;
      s16x8 af[4], bf_[4];
#pragma unroll
      for (int i = 0; i < 4; ++i)
        af[i] = *(const s16x8*)(Ac + (((wr * 64 + i * 16 + lrow) * 128 + cb) ^ swz));
#pragma unroll
      for (int j = 0; j < 4; ++j)
        bf_[j] = *(const s16x8*)(Bc + (((wc * 64 + j * 16 + lrow) * 128 + cb) ^ swz));
#pragma unroll
      for (int i = 0; i < 4; ++i)
#pragma unroll
        for (int j = 0; j < 4; ++j)
          acc[i][j] = __builtin_amdgcn_mfma_f32_16x16x32_bf16(af[i], bf_[j], acc[i][j], 0, 0, 0);
    }
    __syncthreads();
    cur ^= 1;
  }

  for (int j = 0; j < 4; ++j) {
    int col = n0 + wc * 64 + j * 16 + lrow;
    float bvl = bias[col];
    for (int i = 0; i < 4; ++i) {
      int r0 = m0 + wr * 64 + i * 16 + (lg << 2);
      for (int r = 0; r < 4; ++r)
        C[(size_t)(r0 + r) * N + col] = acc[i][j][r] + bvl;
    }
  }
}

// ---------------- causal flash attention v7 (verified: (256,2), VGPR=84, no spill) ----------------
__global__ __launch_bounds__(256, 2) void attn7_kernel(const unsigned short* __restrict__ Qb,
                                                       const unsigned short* __restrict__ Kb,
                                                       const unsigned short* __restrict__ Vt,
                                                       unsigned short* __restrict__ Ob) {
  __shared__ unsigned short Kl[2][4096];
  __shared__ unsigned short Vl[2][4096];

  const int tid = threadIdx.x, lane = tid & 63, wave = tid >> 6;
  const int id = blockIdx.x;
  const int xcd = id & 7;
  const int slot = id >> 3;
  const int bh = (xcd << 3) | (slot >> 4);
  const int ip = slot & 15;
  const size_t base = (size_t)(bh >> 4) * SEQ * E_DIM + (size_t)(bh & 15) * HEAD_D;
  const size_t baset = (size_t)bh * HEAD_D * SEQ;
  const int lq = lane & 15, lg = lane >> 4;

  const int row_lo = ip * 64 + wave * 16 + lq;
  const int row_hi = (31 - ip) * 64 + wave * 16 + lq;

  s16x8 qf0[2], qf1[2];
  {
    const unsigned short* p0 = Qb + base + (size_t)row_lo * E_DIM + lg * 8;
    qf0[0] = *(const s16x8*)p0; qf0[1] = *(const s16x8*)(p0 + 32);
    const unsigned short* p1 = Qb + base + (size_t)row_hi * E_DIM + lg * 8;
    qf1[0] = *(const s16x8*)p1; qf1[1] = *(const s16x8*)(p1 + 32);
  }

  const short onebf = (short)0x3F80;
  const s16x8 ones = {onebf, onebf, onebf, onebf, onebf, onebf, onebf, onebf};

  float m0r = -1e30f, m1r = -1e30f;
  f32x4 o0[4] = {}, o1[4] = {};
  f32x4 l0 = {}, l1 = {};
  const int ntm1 = 31 - ip;
  const bool hi5 = (lane & 32) != 0, hi4 = (lane & 16) != 0;

  const int o0b = tid << 4;
  const int o1b = 4096 + (tid << 4);
  const int r0s = o0b >> 7, r1s = o1b >> 7;
  const int c0s = ((o0b ^ ((r0s & 7) << 4)) & 127) >> 1;
  const int c1s = ((o1b ^ ((r1s & 7) << 4)) & 127) >> 1;
  const int dst0 = wave << 10;
  const int dst1 = 4096 + (wave << 10);

  auto stage = [&](int buf, int k0) {
    gld16((const void*)(Kb + base + (size_t)(k0 + r0s) * E_DIM + c0s),
          (void*)((char*)&Kl[buf][0] + dst0));
    gld16((const void*)(Kb + base + (size_t)(k0 + r1s) * E_DIM + c1s),
          (void*)((char*)&Kl[buf][0] + dst1));
    gld16((const void*)(Vt + baset + (size_t)r0s * SEQ + k0 + c0s),
          (void*)((char*)&Vl[buf][0] + dst0));
    gld16((const void*)(Vt + baset + (size_t)r1s * SEQ + k0 + c1s),
          (void*)((char*)&Vl[buf][0] + dst1));
  };

  const int swz = (lq & 7) << 4;

  auto process = [&](f32x4 (&sv)[4], int qrow, bool diag, float& mreg,
                     f32x4 (&oacc)[4], f32x4& lacc, int kk0, s16x8 (&vf)[4][2]) {
    if (diag) {
#pragma unroll
      for (int kb = 0; kb < 4; ++kb)
#pragma unroll
        for (int r = 0; r < 4; ++r) {
          int kk = kk0 + kb * 16 + lg * 4 + r;
          if (kk > qrow) sv[kb][r] = -1e30f;
        }
    }
    float t0, t1, mk[4];
#pragma unroll
    for (int kb = 0; kb < 4; ++kb) {
      t0 = fmaxf(sv[kb][0], sv[kb][1]);
      t1 = fmaxf(sv[kb][2], sv[kb][3]);
      mk[kb] = fmaxf(t0, t1);
    }
    float mx = fmaxf(fmaxf(mk[0], mk[1]), fmaxf(mk[2], mk[3]));
    mx = fmaxf(mx, __shfl_xor(mx, 16, 64));
    mx = fmaxf(mx, __shfl_xor(mx, 32, 64));
    if (!__all(mx - mreg <= 8.0f)) {
      float mn = fmaxf(mreg, mx);
      float corr = __builtin_amdgcn_exp2f(mreg - mn);
#pragma unroll
      for (int db = 0; db < 4; ++db) oacc[db] = oacc[db] * corr;
      lacc = lacc * corr;
      mreg = mn;
    }
    const float mn = mreg;
    unsigned c[4][2];
#pragma unroll
    for (int kb = 0; kb < 4; ++kb)
#pragma unroll
      for (int rp = 0; rp < 2; ++rp) {
        float plo = __builtin_amdgcn_exp2f(sv[kb][2 * rp] - mn);
        float phi = __builtin_amdgcn_exp2f(sv[kb][2 * rp + 1] - mn);
        c[kb][rp] = packbf2(plo, phi);
      }
#pragma unroll
    for (int k1 = 0; k1 < 2; ++k1)
#pragma unroll
      for (int rp = 0; rp < 2; ++rp)
        swap32(c[2 * k1][rp], c[2 * k1 + 1][rp], hi5);
#pragma unroll
    for (int k1 = 0; k1 < 2; ++k1)
#pragma unroll
      for (int rp = 0; rp < 2; ++rp)
        swap16(c[2 * k1][rp], c[2 * k1 + 1][rp], hi4);
#pragma unroll
    for (int ks = 0; ks < 2; ++ks) {
      union { unsigned w[4]; s16x8 v; } pu;
      pu.w[0] = c[2 * ks][0]; pu.w[1] = c[2 * ks][1];
      pu.w[2] = c[2 * ks + 1][0]; pu.w[3] = c[2 * ks + 1][1];
      lacc = __builtin_amdgcn_mfma_f32_16x16x32_bf16(ones, pu.v, lacc, 0, 0, 0);
#pragma unroll
      for (int db = 0; db < 4; ++db)
        oacc[db] = __builtin_amdgcn_mfma_f32_16x16x32_bf16(vf[db][ks], pu.v, oacc[db], 0, 0, 0);
    }
  };

  stage(0, 0);
  __syncthreads();
  int cur = 0;

  for (int t = 0; t <= ntm1; ++t) {
    if (t < ntm1) stage(cur ^ 1, (t + 1) * 64);

    const char* Kc = (const char*)&Kl[cur][0];
    const char* Vc = (const char*)&Vl[cur][0];
    s16x8 kf[4][2];
#pragma unroll
    for (int kb = 0; kb < 4; ++kb)
#pragma unroll
      for (int j = 0; j < 2; ++j)
        kf[kb][j] = *(const s16x8*)(Kc + (((kb * 16 + lq) * 128 + j * 64 + lg * 16) ^ swz));
    s16x8 vf[4][2];
#pragma unroll
    for (int db = 0; db < 4; ++db)
#pragma unroll
      for (int ks = 0; ks < 2; ++ks)
        vf[db][ks] = *(const s16x8*)(Vc + (((db * 16 + lq) * 128 + ks * 64 + lg * 16) ^ swz));

    const int kk0 = t * 64;
    {
      f32x4 s1v[4] = {};
#pragma unroll
      for (int kb = 0; kb < 4; ++kb) {
        s1v[kb] = __builtin_amdgcn_mfma_f32_16x16x32_bf16(kf[kb][0], qf1[0], s1v[kb], 0, 0, 0);
        s1v[kb] = __builtin_amdgcn_mfma_f32_16x16x32_bf16(kf[kb][1], qf1[1], s1v[kb], 0, 0, 0);
      }
      process(s1v, row_hi, t == ntm1, m1r, o1, l1, kk0, vf);
    }
    if (t <= ip) {
      f32x4 s0v[4] = {};
#pragma unroll
      for (int kb = 0; kb < 4; ++kb) {
        s0v[kb] = __builtin_amdgcn_mfma_f32_16x16x32_bf16(kf[kb][0], qf0[0], s0v[kb], 0, 0, 0);
        s0v[kb] = __builtin_amdgcn_mfma_f32_16x16x32_bf16(kf[kb][1], qf0[1], s0v[kb], 0, 0, 0);
      }
      process(s0v, row_lo, t == ip, m0r, o0, l0, kk0, vf);
    }

    __syncthreads();
    cur ^= 1;
  }

  {
    float inv0 = 1.0f / l0[0], inv1 = 1.0f / l1[0];
#pragma unroll
    for (int db = 0; db < 4; ++db) {
      ushort4 w0, w1;
      w0.x = f2b(o0[db][0] * inv0); w0.y = f2b(o0[db][1] * inv0);
      w0.z = f2b(o0[db][2] * inv0); w0.w = f2b(o0[db][3] * inv0);
      w1.x = f2b(o1[db][0] * inv1); w1.y = f2b(o1[db][1] * inv1);
      w1.z = f2b(o1[db][2] * inv1); w1.w = f2b(o1[db][3] * inv1);
      *(ushort4*)&Ob[base + (size_t)row_lo * E_DIM + db * 16 + lg * 4] = w0;
      *(ushort4*)&Ob[base + (size_t)row_hi * E_DIM + db * 16 + lg * 4] = w1;
    }
  }
}

extern "C" void kernel_launch(void* const* d_in, const int* in_sizes, int n_in,
                              void* d_out, int out_size, void* d_ws, size_t ws_size,
                              hipStream_t stream) {
  const float* x    = (const float*)d_in[0];
  const float* wq_w = (const float*)d_in[1];
  const float* wq_b = (const float*)d_in[2];
  const float* wk_w = (const float*)d_in[3];
  const float* wk_b = (const float*)d_in[4];
  const float* wv_w = (const float*)d_in[5];
  const float* wv_b = (const float*)d_in[6];
  const float* wo_w = (const float*)d_in[7];
  const float* wo_b = (const float*)d_in[8];
  float* out = (float*)d_out;

  const size_t XE = (size_t)M_ROWS * E_DIM;
  const size_t WE = (size_t)E_DIM * E_DIM;
  char* ws = (char*)d_ws;
  unsigned short* xb    = (unsigned short*)ws; ws += XE * 2;
  unsigned short* wqkvT = (unsigned short*)ws; ws += 3 * WE * 2;  // [3072][1024]
  unsigned short* woT   = (unsigned short*)ws; ws += WE * 2;
  unsigned short* Qb    = (unsigned short*)ws; ws += XE * 2;
  unsigned short* Kb    = (unsigned short*)ws; ws += XE * 2;
  unsigned short* Vt    = (unsigned short*)ws; ws += XE * 2;  // [bh*64+d][s]
  unsigned short* Ao    = (unsigned short*)ws; ws += XE * 2;

  cast_x_kernel<<<2048, 256, 0, stream>>>(x, xb, (int)(XE / 4));
  wtrans4_kernel<<<dim3(E_DIM / 64, E_DIM / 64, 4), 256, 0, stream>>>(
      wq_w, wk_w, wv_w, wo_w, wqkvT, wqkvT + WE, wqkvT + 2 * WE, woT);

  gemm_qkv<<<dim3(M_ROWS / 128, 3072 / 128), 256, 0, stream>>>(
      xb, wqkvT, wq_b, wk_b, wv_b, Qb, Kb, Vt);

  attn7_kernel<<<1024, 256, 0, stream>>>(Qb, Kb, Vt, Ao);

  gemm_out<<<dim3(M_ROWS / 128, E_DIM / 128), 256, 0, stream>>>(Ao, woT, wo_b, out);
}